// Round 3
// baseline (1038.769 us; speedup 1.0000x reference)
//
#include <hip/hip_runtime.h>

// FutureTrajDecoder: 3-layer GRU rollout, B=16384, ES=HS=64, T=128, NOUT=2.
// R16: same systolic skeleton; attacks the now-confirmed bottleneck.
// Evidence: R13 (polls) = R14 (syncthreads) = R15 (lgkm barrier) = 450us.
// Stage wall ~1850 cyc vs ~1000 cyc issue demand per SIMD (VALUBusy 54% x
// 1850 = 1000 ✓): ~45% of issue slots idle from per-wave dependency latency
// (ds_read -> 4-deep MFMA chain -> 6-deep trans chain -> ds_write) with only
// 3 waves/SIMD of TLP. Sync mechanism was never the problem.
// Changes (math-equivalent except rcp-merge rounding):
//  1. 16 waves (1024 thr): 4th wave per SIMD = dedicated OUT pipeline stage
//     (lag 3). Removes out-proj MFMAs + global store from L0's critical
//     wave; extra wave fills issue holes; uniform epilogue, no tail hack.
//  2. h-frag register prefetch (E/O double-buffered): own-layer h(t-1) was
//     written >=4 stages ago -> prefetch 1 stage early. Post-barrier the
//     6 h-MFMAs issue with zero LDS wait and cover the x-load latency
//     (x issued before pf, so lgkmcnt waits exclude the pf).
//     Prefetch is race-free: prefetched tile != any tile written this stage.
//  3. rcp-merge: r = Q*(1+Ez), z = Q*(1+Er), Q = rcp((1+Er)(1+Ez)):
//     5 trans/elem instead of 6 (-17% of the 576 cyc/SIMD/stage trans floor).
//  4. launch_bounds(1024,4): VGPR cap 128 (est ~100-120, no spill cliff).
// Kept: barrier = s_waitcnt lgkmcnt(0)+s_barrier (no vmcnt drain); parity
// double-buffer; emb folded into L0; gate scales folded into weights;
// biases in MFMA C-init; weights = A operand; fp32 carry in VGPRs;
// MFMA 16x16x32 f16 fp32-accum; x-MFMAs chained.

#define ESZ   64
#define HSZ   64
#define TLEN  128
#define NOUTC 2
#define LDW   72              // fp16 row stride (144 B)
#define TB16  (16*LDW)        // one 16-row activation tile buffer
#define L2E   1.44269504f

typedef _Float16 half8 __attribute__((ext_vector_type(8)));
typedef _Float16 half4 __attribute__((ext_vector_type(4)));
typedef float    floatx4 __attribute__((ext_vector_type(4)));
typedef float    floatx2 __attribute__((ext_vector_type(2)));

#define MFMA(a, b, c) __builtin_amdgcn_mfma_f32_16x16x32_f16((a), (b), (c), 0, 0, 0)

// LDS-ordering barrier WITHOUT vmcnt drain (global stores stay in flight).
#define SBAR() asm volatile("s_waitcnt lgkmcnt(0)\n\ts_barrier" ::: "memory")

__global__ __launch_bounds__(1024, 4) void gru_pipe(
    const float* __restrict__ enc,     // (B, 64)
    const float* __restrict__ emb_w,   // (64, 64)
    const float* __restrict__ emb_b,   // (64,)
    const float* __restrict__ w_ih,    // (3, 192, 64)
    const float* __restrict__ w_hh,    // (3, 192, 64)
    const float* __restrict__ b_ih,    // (3, 192)
    const float* __restrict__ b_hh,    // (3, 192)
    const float* __restrict__ out_w,   // (2, 64)
    const float* __restrict__ out_b,   // (2,)
    float* __restrict__ out)           // (B, 128, 2)
{
    __shared__ _Float16 s_hl[3 * 4 * 2 * TB16]; // h_l fp16 [layer][tile][parity]
    __shared__ float    s_btmp[3 * 64];          // folded emb bias (fp32)

    const int tid  = threadIdx.x;
    const int wave = tid >> 6, lane = tid & 63;
    const int l = wave >> 2, g = wave & 3;      // pipeline stage 0..3 (3=OUT), colgroup
    const int q = lane >> 4, c = lane & 15;
    const int u  = (g << 4) | c;                // weight row this lane loads
    const int u4 = (g << 4) | (q << 2);         // first hidden unit this lane OWNS
    const long wgbase = (long)blockIdx.x * 64;

    // ---- stage enc (= x(0) = h(-1)) into all layer buffers, parity 1 ----
    if (tid < 512) {
        const int row = tid >> 3, k0 = (tid & 7) << 3;   // 8 floats per thread
        const int j = row >> 4, rr = row & 15;
        const float* p = enc + (wgbase + row) * ESZ + k0;
        floatx4 s0 = *(const floatx4*)p;
        floatx4 s1 = *(const floatx4*)(p + 4);
        half8 v;
        #pragma unroll
        for (int x = 0; x < 4; ++x) { v[x] = (_Float16)s0[x]; v[4 + x] = (_Float16)s1[x]; }
        #pragma unroll
        for (int ly = 0; ly < 3; ++ly)
            *(half8*)&s_hl[((ly * 4 + j) * 2 + 1) * TB16 + rr * LDW + k0] = v;
    }

    // ---- weight fragments (A-operand) ----
    auto ldw8s = [&](const float* p, float sc) {
        floatx4 a = *(const floatx4*)p, b = *(const floatx4*)(p + 4);
        half8 v;
        #pragma unroll
        for (int x = 0; x < 4; ++x) { v[x] = (_Float16)(a[x] * sc); v[4 + x] = (_Float16)(b[x] * sc); }
        return v;
    };
    half8 fR[4], fZ[4], fNi[2], fNh[2], fO[2];
    if (l == 0) {
        // ---- fold W' = W_ih0 @ W_e (fp32), b' = W_ih0 @ b_e ----
        const float* wi = w_ih;
        const float* wh = w_hh;
        floatx4 aR[4], aZ[4], aN[4];
        #pragma unroll
        for (int x = 0; x < 4; ++x) { aR[x] = {0,0,0,0}; aZ[x] = {0,0,0,0}; aN[x] = {0,0,0,0}; }
        float bR = 0.f, bZ = 0.f, bN = 0.f;
        for (int k4 = 0; k4 < 64; k4 += 4) {
            floatx4 wr4 = *(const floatx4*)(wi + (u) * 64 + k4);
            floatx4 wz4 = *(const floatx4*)(wi + (64 + u) * 64 + k4);
            floatx4 wn4 = *(const floatx4*)(wi + (128 + u) * 64 + k4);
            floatx4 be4 = *(const floatx4*)(emb_b + k4);
            #pragma unroll
            for (int kk = 0; kk < 4; ++kk) {
                const float* er = emb_w + (k4 + kk) * 64;
                floatx4 e0 = *(const floatx4*)(er + q * 8);
                floatx4 e1 = *(const floatx4*)(er + q * 8 + 4);
                floatx4 e2 = *(const floatx4*)(er + 32 + q * 8);
                floatx4 e3 = *(const floatx4*)(er + 32 + q * 8 + 4);
                const float wr = wr4[kk], wz = wz4[kk], wn = wn4[kk];
                aR[0] += wr * e0; aR[1] += wr * e1; aR[2] += wr * e2; aR[3] += wr * e3;
                aZ[0] += wz * e0; aZ[1] += wz * e1; aZ[2] += wz * e2; aZ[3] += wz * e3;
                aN[0] += wn * e0; aN[1] += wn * e1; aN[2] += wn * e2; aN[3] += wn * e3;
                bR += wr * be4[kk]; bZ += wz * be4[kk]; bN += wn * be4[kk];
            }
        }
        #pragma unroll
        for (int x = 0; x < 4; ++x) {
            fR[0][x] = (_Float16)(-L2E * aR[0][x]);   fR[0][4 + x] = (_Float16)(-L2E * aR[1][x]);
            fR[1][x] = (_Float16)(-L2E * aR[2][x]);   fR[1][4 + x] = (_Float16)(-L2E * aR[3][x]);
            fZ[0][x] = (_Float16)(-L2E * aZ[0][x]);   fZ[0][4 + x] = (_Float16)(-L2E * aZ[1][x]);
            fZ[1][x] = (_Float16)(-L2E * aZ[2][x]);   fZ[1][4 + x] = (_Float16)(-L2E * aZ[3][x]);
            fNi[0][x] = (_Float16)(2*L2E * aN[0][x]); fNi[0][4 + x] = (_Float16)(2*L2E * aN[1][x]);
            fNi[1][x] = (_Float16)(2*L2E * aN[2][x]); fNi[1][4 + x] = (_Float16)(2*L2E * aN[3][x]);
        }
        fR[2]  = ldw8s(wh + (u) * 64 + q * 8, -L2E);        fR[3]  = ldw8s(wh + (u) * 64 + 32 + q * 8, -L2E);
        fZ[2]  = ldw8s(wh + (64 + u) * 64 + q * 8, -L2E);   fZ[3]  = ldw8s(wh + (64 + u) * 64 + 32 + q * 8, -L2E);
        fNh[0] = ldw8s(wh + (128 + u) * 64 + q * 8, 2*L2E); fNh[1] = ldw8s(wh + (128 + u) * 64 + 32 + q * 8, 2*L2E);
        if (q == 0) {                                // fold-bias per hidden unit u (q-invariant)
            s_btmp[u] = bR; s_btmp[64 + u] = bZ; s_btmp[128 + u] = bN;
        }
    } else if (l < 3) {
        const float* wi = w_ih + l * 3 * HSZ * ESZ;
        const float* wh = w_hh + l * 3 * HSZ * ESZ;
        fR[0]  = ldw8s(wi + (u) * 64 + q * 8, -L2E);        fR[1]  = ldw8s(wi + (u) * 64 + 32 + q * 8, -L2E);
        fR[2]  = ldw8s(wh + (u) * 64 + q * 8, -L2E);        fR[3]  = ldw8s(wh + (u) * 64 + 32 + q * 8, -L2E);
        fZ[0]  = ldw8s(wi + (64 + u) * 64 + q * 8, -L2E);   fZ[1]  = ldw8s(wi + (64 + u) * 64 + 32 + q * 8, -L2E);
        fZ[2]  = ldw8s(wh + (64 + u) * 64 + q * 8, -L2E);   fZ[3]  = ldw8s(wh + (64 + u) * 64 + 32 + q * 8, -L2E);
        fNi[0] = ldw8s(wi + (128 + u) * 64 + q * 8, 2*L2E); fNi[1] = ldw8s(wi + (128 + u) * 64 + 32 + q * 8, 2*L2E);
        fNh[0] = ldw8s(wh + (128 + u) * 64 + q * 8, 2*L2E); fNh[1] = ldw8s(wh + (128 + u) * 64 + 32 + q * 8, 2*L2E);
    } else {
        // OUT waves: only the out-projection fragments
        const int oc = (c < NOUTC) ? c : 0;
        fO[0] = ldw8s(out_w + oc * 64 + q * 8, 1.f);
        fO[1] = ldw8s(out_w + oc * 64 + 32 + q * 8, 1.f);
    }
    __syncthreads();                                 // staging + s_btmp visible

    // ---- per-lane bias vectors (C-init), hidden units u4..u4+3 ----
    floatx4 bR4, bZ4, bNi4, bNh4;
    if (l == 0) {
        #pragma unroll
        for (int i = 0; i < 4; ++i) {
            bR4[i]  = -L2E * (s_btmp[u4 + i] + b_ih[u4 + i] + b_hh[u4 + i]);
            bZ4[i]  = -L2E * (s_btmp[64 + u4 + i] + b_ih[64 + u4 + i] + b_hh[64 + u4 + i]);
            bNi4[i] = 2.f * L2E * (s_btmp[128 + u4 + i] + b_ih[128 + u4 + i]);
            bNh4[i] = 2.f * L2E * b_hh[128 + u4 + i];
        }
    } else if (l < 3) {
        const int b0 = l * 192;
        floatx4 bi0 = *(const floatx4*)(b_ih + b0 + u4),       bh0 = *(const floatx4*)(b_hh + b0 + u4);
        floatx4 bi1 = *(const floatx4*)(b_ih + b0 + 64 + u4),  bh1 = *(const floatx4*)(b_hh + b0 + 64 + u4);
        floatx4 bi2 = *(const floatx4*)(b_ih + b0 + 128 + u4), bh2 = *(const floatx4*)(b_hh + b0 + 128 + u4);
        #pragma unroll
        for (int i = 0; i < 4; ++i) {
            bR4[i]  = -L2E * (bi0[i] + bh0[i]);
            bZ4[i]  = -L2E * (bi1[i] + bh1[i]);
            bNi4[i] = 2.f * L2E * bi2[i];
            bNh4[i] = 2.f * L2E * bh2[i];
        }
    }
    const float ob0 = out_b[0], ob1 = out_b[1];

    // ---- fp32 h-carry in VGPRs: ca{j}[i] = h[u4+i][batch row j*16+c] ----
    floatx4 ca0 = *(const floatx4*)(enc + (wgbase +  0 + c) * 64 + u4);
    floatx4 ca1 = *(const floatx4*)(enc + (wgbase + 16 + c) * 64 + u4);
    floatx4 ca2 = *(const floatx4*)(enc + (wgbase + 32 + c) * 64 + u4);
    floatx4 ca3 = *(const floatx4*)(enc + (wgbase + 48 + c) * 64 + u4);

    const int ar = c * LDW + (q << 3);               // act B-frag offset

    // one pipeline-stage action for a layer wave: optional visit (with x-load
    // issued FIRST so its lgkm wait excludes the prefetch) + unconditional
    // h-prefetch for this wave's NEXT visit (data >=3 stages old; the
    // prefetched tile is never written in the current stage -> race-free).
    auto stageL = [&](const int ll, const int j, const int parw, const bool valid,
                      half8& cah0, half8& cah1,      // consumed prefetched h-frags
                      half8& pah0, half8& pah1,      // produced prefetch (next stage)
                      const int nj, const int npw,
                      floatx4& cs) {
        half8 bx0, bx1;
        if (valid) {
            const _Float16* xb = (ll == 0) ? s_hl + ((8 + j) * 2 + (parw ^ 1)) * TB16
                                           : s_hl + (((ll - 1) * 4 + j) * 2 + parw) * TB16;
            bx0 = *(const half8*)(xb + ar);
            bx1 = *(const half8*)(xb + ar + 32);
        }
        {   // prefetch next h (always, so skipped visits still feed the pipe)
            const _Float16* nhb = s_hl + ((ll * 4 + nj) * 2 + (npw ^ 1)) * TB16;
            pah0 = *(const half8*)(nhb + ar);
            pah1 = *(const half8*)(nhb + ar + 32);
        }
        if (valid) {
            floatx4 accr = bR4, accz = bZ4, accnh = bNh4;
            accr  = MFMA(fR[2], cah0, accr);   accr  = MFMA(fR[3], cah1, accr);
            accz  = MFMA(fZ[2], cah0, accz);   accz  = MFMA(fZ[3], cah1, accz);
            accnh = MFMA(fNh[0], cah0, accnh); accnh = MFMA(fNh[1], cah1, accnh);
            accr = MFMA(fR[0], bx0, accr); accr = MFMA(fR[1], bx1, accr);
            accz = MFMA(fZ[0], bx0, accz); accz = MFMA(fZ[1], bx1, accz);
            floatx4 accni = bNi4;
            accni = MFMA(fNi[0], bx0, accni); accni = MFMA(fNi[1], bx1, accni);
            _Float16* hw = s_hl + ((ll * 4 + j) * 2 + parw) * TB16 + c * LDW + u4;
            half4 hv4; floatx4 hnew;
            #pragma unroll
            for (int i = 0; i < 4; ++i) {
                const float er = __builtin_amdgcn_exp2f(accr[i]);
                const float ez = __builtin_amdgcn_exp2f(accz[i]);
                const float pr = 1.f + er, pz = 1.f + ez;
                const float qq = __builtin_amdgcn_rcpf(pr * pz);  // shared rcp
                const float rr = qq * pz;                          // = 1/(1+er)
                const float zz = qq * pr;                          // = 1/(1+ez)
                const float a  = accni[i] + rr * accnh[i];
                const float n  = 1.f - 2.f * __builtin_amdgcn_rcpf(1.f + __builtin_amdgcn_exp2f(a));
                const float hv = n + zz * (cs[i] - n);
                hnew[i] = hv; hv4[i] = (_Float16)hv;
            }
            *(half4*)hw = hv4;
            cs = hnew;
        }
    };

    // OUT pipeline stage: out(t) = h2(t) @ out_w.T + out_b; wave g owns tile g.
    auto visO = [&](const int j, const int t, const int parw) {
        if (g != j) return;
        const _Float16* xb = s_hl + ((8 + j) * 2 + parw) * TB16;
        half8 b0 = *(const half8*)(xb + ar);
        half8 b1 = *(const half8*)(xb + ar + 32);
        floatx4 oa = {ob0, ob1, 0.f, 0.f};
        oa = MFMA(fO[0], b0, oa);
        oa = MFMA(fO[1], b1, oa);
        if (q == 0) {
            const long row = wgbase + j * 16 + c;
            *(floatx2*)(out + (row * TLEN + t) * NOUTC) = floatx2{oa[0], oa[1]};
        }
    };

    // ---- prime the E prefetch set for stage 0 (t0 = 0) ----
    half8 eh0, eh1, oh0, oh1;
    if (l < 3) {
        const int j0 = (l == 0) ? 0 : (l == 1) ? 3 : 2;  // first-visit tile
        const int p0 = (l == 0) ? 1 : 0;                 // its h parity (parw^1)
        const _Float16* phb = s_hl + ((l * 4 + j0) * 2 + p0) * TB16;
        eh0 = *(const half8*)(phb + ar);
        eh1 = *(const half8*)(phb + ar + 32);
    }

    // ---- systolic loop: 8 stages per 2 timesteps; E/O prefetch sets alternate ----
    for (int s4 = 0; s4 < TLEN; s4 += 2) {
        const bool vv = (s4 != 0);
        // stage 0 (E->O)
        if (l == 0)      stageL(0, 0, 0, true, eh0, eh1, oh0, oh1, 1, 0, ca0);
        else if (l == 1) stageL(1, 3, 1, vv,   eh0, eh1, oh0, oh1, 0, 0, ca3);
        else if (l == 2) stageL(2, 2, 1, vv,   eh0, eh1, oh0, oh1, 3, 1, ca2);
        else if (vv)     visO(1, s4 - 1, 1);
        SBAR();
        // stage 1 (O->E)
        if (l == 0)      stageL(0, 1, 0, true, oh0, oh1, eh0, eh1, 2, 0, ca1);
        else if (l == 1) stageL(1, 0, 0, true, oh0, oh1, eh0, eh1, 1, 0, ca0);
        else if (l == 2) stageL(2, 3, 1, vv,   oh0, oh1, eh0, eh1, 0, 0, ca3);
        else if (vv)     visO(2, s4 - 1, 1);
        SBAR();
        // stage 2 (E->O)
        if (l == 0)      stageL(0, 2, 0, true, eh0, eh1, oh0, oh1, 3, 0, ca2);
        else if (l == 1) stageL(1, 1, 0, true, eh0, eh1, oh0, oh1, 2, 0, ca1);
        else if (l == 2) stageL(2, 0, 0, true, eh0, eh1, oh0, oh1, 1, 0, ca0);
        else if (vv)     visO(3, s4 - 1, 1);
        SBAR();
        // stage 3 (O->E)
        if (l == 0)      stageL(0, 3, 0, true, oh0, oh1, eh0, eh1, 0, 1, ca3);
        else if (l == 1) stageL(1, 2, 0, true, oh0, oh1, eh0, eh1, 3, 0, ca2);
        else if (l == 2) stageL(2, 1, 0, true, oh0, oh1, eh0, eh1, 2, 0, ca1);
        else             visO(0, s4, 0);
        SBAR();
        // stage 4 (E->O)
        if (l == 0)      stageL(0, 0, 1, true, eh0, eh1, oh0, oh1, 1, 1, ca0);
        else if (l == 1) stageL(1, 3, 0, true, eh0, eh1, oh0, oh1, 0, 1, ca3);
        else if (l == 2) stageL(2, 2, 0, true, eh0, eh1, oh0, oh1, 3, 0, ca2);
        else             visO(1, s4, 0);
        SBAR();
        // stage 5 (O->E)
        if (l == 0)      stageL(0, 1, 1, true, oh0, oh1, eh0, eh1, 2, 1, ca1);
        else if (l == 1) stageL(1, 0, 1, true, oh0, oh1, eh0, eh1, 1, 1, ca0);
        else if (l == 2) stageL(2, 3, 0, true, oh0, oh1, eh0, eh1, 0, 1, ca3);
        else             visO(2, s4, 0);
        SBAR();
        // stage 6 (E->O)
        if (l == 0)      stageL(0, 2, 1, true, eh0, eh1, oh0, oh1, 3, 1, ca2);
        else if (l == 1) stageL(1, 1, 1, true, eh0, eh1, oh0, oh1, 2, 1, ca1);
        else if (l == 2) stageL(2, 0, 1, true, eh0, eh1, oh0, oh1, 1, 1, ca0);
        else             visO(3, s4, 0);
        SBAR();
        // stage 7 (O->E)
        if (l == 0)      stageL(0, 3, 1, true, oh0, oh1, eh0, eh1, 0, 0, ca3);
        else if (l == 1) stageL(1, 2, 1, true, oh0, oh1, eh0, eh1, 3, 1, ca2);
        else if (l == 2) stageL(2, 1, 1, true, oh0, oh1, eh0, eh1, 2, 1, ca1);
        else             visO(0, s4 + 1, 1);
        SBAR();
    }

    // ---- epilogue: finish t = 127 leftovers (parity 1) ----
    // E0 (consume E, pf into O where still needed)
    if (l == 1)      stageL(1, 3, 1, true, eh0, eh1, oh0, oh1, 0, 0, ca3);
    else if (l == 2) stageL(2, 2, 1, true, eh0, eh1, oh0, oh1, 3, 1, ca2);
    else if (l == 3) visO(1, TLEN - 1, 1);
    SBAR();
    // E1 (consume O)
    if (l == 2)      stageL(2, 3, 1, true, oh0, oh1, eh0, eh1, 0, 0, ca3);
    else if (l == 3) visO(2, TLEN - 1, 1);
    SBAR();
    // E2
    if (l == 3) visO(3, TLEN - 1, 1);
}

extern "C" void kernel_launch(void* const* d_in, const int* in_sizes, int n_in,
                              void* d_out, int out_size, void* d_ws, size_t ws_size,
                              hipStream_t stream) {
    (void)in_sizes; (void)n_in; (void)d_ws; (void)ws_size; (void)out_size;
    const int grid = 16384 / 64;   // 256 workgroups, 1 per CU
    gru_pipe<<<grid, 1024, 0, stream>>>(
        (const float*)d_in[0],  // agentFutureTrajEnc
        (const float*)d_in[1],  // emb_w
        (const float*)d_in[2],  // emb_b
        (const float*)d_in[3],  // w_ih
        (const float*)d_in[4],  // w_hh
        (const float*)d_in[5],  // b_ih
        (const float*)d_in[6],  // b_hh
        (const float*)d_in[7],  // out_w
        (const float*)d_in[8],  // out_b
        (float*)d_out);
}

// Round 4
// 547.327 us; speedup vs baseline: 1.8979x; 1.8979x over previous
//
#include <hip/hip_runtime.h>

// FutureTrajDecoder: 3-layer GRU rollout, B=16384, ES=HS=64, T=128, NOUT=2.
// R17: 2 independent WGs per CU (grid 512 x 32 rows) to double TLP.
// Evidence trail: R13(polls)=R14(syncthreads)=R15(lgkm-barrier)=450us ->
// sync mechanism irrelevant. VALUBusy 54%, MfmaUtil 30%, LDS ~40%: nothing
// saturated; stage wall 1850 cyc vs ~1000 cyc issue demand per SIMD. The
// binding constraint is 1 WG/CU (grid=256) = 3 waves/SIMD: per-wave dep
// latency (ds_read -> chained MFMA -> 6-deep trans) can't be hidden.
// R16 lesson: launch_bounds(1024,4) capped VGPR at 64 -> scratch spills
// (WRITE_SIZE 16->198MB) -> 1038us. Never over-promise occupancy.
// Changes vs R15 (math identical except rcp-merge, which R16 verified
// bit-compatible: absmax unchanged):
//  1. WG = 32 rows (2 tiles of 16), grid = 512 -> 2 WGs/CU, 6 waves/SIMD.
//     J=2 tiles needs 3 slots/t (J=2 with lag-2 races same-slot); each
//     layer wave idles 1 of 3 slots; the OTHER WG fills those issue holes.
//     VGPR 76x6=456<=512 ok; LDS 28.5KBx2=57KB ok; 24 waves/CU ok.
//  2. rcp-merge: Q=rcp((1+Er)(1+Ez)); r=Q*(1+Ez), z=Q*(1+Er):
//     5 trans/elem instead of 6.
//  3. 3 barriers/t (was 4). launch_bounds(768,3) kept (honest; VGPR must
//     stay <=85 for 2-WG co-residency -- watch VGPR_Count).
// Schedule per t (parw = t&1):  [slot: wave -> cell]
//   p=0: L0 (t,0);            L2 (t-1,1)         ; L1 idle
//   p=1: L0 (t,1); L1 (t,0);                     ; L2 idle
//   p=2: L1 (t,1); L2 (t,0);  L0 g<2: out(t-1,g)
// All producer->consumer pairs separated by >=1 barrier; parity (t&1)
// double-buffer gives >=3-slot WAR gaps. Epilogue: L2(127,1)+out(127,0),
// then out(127,1).
// Kept: SBAR = s_waitcnt lgkmcnt(0)+s_barrier (no vmcnt drain); emb folded
// into L0; gate scales folded into weights; biases in MFMA C-init; weights
// = A operand; fp32 carry in VGPRs; MFMA 16x16x32 f16 fp32-accum; x-MFMAs
// chained; out-proj on L0 waves (fO was already in their 76-VGPR budget).

#define ESZ   64
#define HSZ   64
#define TLEN  128
#define NOUTC 2
#define LDW   72              // fp16 row stride (144 B)
#define TB16  (16*LDW)        // one 16-row activation tile buffer
#define L2E   1.44269504f

typedef _Float16 half8 __attribute__((ext_vector_type(8)));
typedef _Float16 half4 __attribute__((ext_vector_type(4)));
typedef float    floatx4 __attribute__((ext_vector_type(4)));
typedef float    floatx2 __attribute__((ext_vector_type(2)));

#define MFMA(a, b, c) __builtin_amdgcn_mfma_f32_16x16x32_f16((a), (b), (c), 0, 0, 0)

// LDS-ordering barrier WITHOUT vmcnt drain (global stores stay in flight).
#define SBAR() asm volatile("s_waitcnt lgkmcnt(0)\n\ts_barrier" ::: "memory")

__global__ __launch_bounds__(768, 3) void gru_pipe(
    const float* __restrict__ enc,     // (B, 64)
    const float* __restrict__ emb_w,   // (64, 64)
    const float* __restrict__ emb_b,   // (64,)
    const float* __restrict__ w_ih,    // (3, 192, 64)
    const float* __restrict__ w_hh,    // (3, 192, 64)
    const float* __restrict__ b_ih,    // (3, 192)
    const float* __restrict__ b_hh,    // (3, 192)
    const float* __restrict__ out_w,   // (2, 64)
    const float* __restrict__ out_b,   // (2,)
    float* __restrict__ out)           // (B, 128, 2)
{
    __shared__ _Float16 s_hl[3 * 2 * 2 * TB16]; // h_l fp16 [layer][tile][parity]
    __shared__ float    s_btmp[3 * 64];          // folded emb bias (fp32)

    const int tid  = threadIdx.x;
    const int wave = tid >> 6, lane = tid & 63;
    const int l = wave >> 2, g = wave & 3;      // layer-stage 0..2, colgroup 0..3
    const int q = lane >> 4, c = lane & 15;
    const int u  = (g << 4) | c;                // weight row this lane loads
    const int u4 = (g << 4) | (q << 2);         // first hidden unit this lane OWNS
    const long wgbase = (long)blockIdx.x * 32;

    // ---- stage enc (= x(0) = h(-1)) into all layer buffers, parity 1 ----
    if (tid < 256) {
        const int row = tid >> 3, k0 = (tid & 7) << 3;   // 8 floats per thread
        const int j = row >> 4, rr = row & 15;
        const float* p = enc + (wgbase + row) * ESZ + k0;
        floatx4 s0 = *(const floatx4*)p;
        floatx4 s1 = *(const floatx4*)(p + 4);
        half8 v;
        #pragma unroll
        for (int x = 0; x < 4; ++x) { v[x] = (_Float16)s0[x]; v[4 + x] = (_Float16)s1[x]; }
        #pragma unroll
        for (int ly = 0; ly < 3; ++ly)
            *(half8*)&s_hl[((ly * 2 + j) * 2 + 1) * TB16 + rr * LDW + k0] = v;
    }

    // ---- weight fragments (A-operand) ----
    auto ldw8s = [&](const float* p, float sc) {
        floatx4 a = *(const floatx4*)p, b = *(const floatx4*)(p + 4);
        half8 v;
        #pragma unroll
        for (int x = 0; x < 4; ++x) { v[x] = (_Float16)(a[x] * sc); v[4 + x] = (_Float16)(b[x] * sc); }
        return v;
    };
    half8 fR[4], fZ[4], fNi[2], fNh[2], fO[2];
    fO[0] = fO[1] = half8{};
    if (l == 0) {
        // ---- fold W' = W_ih0 @ W_e (fp32), b' = W_ih0 @ b_e ----
        const float* wi = w_ih;
        const float* wh = w_hh;
        floatx4 aR[4], aZ[4], aN[4];
        #pragma unroll
        for (int x = 0; x < 4; ++x) { aR[x] = {0,0,0,0}; aZ[x] = {0,0,0,0}; aN[x] = {0,0,0,0}; }
        float bR = 0.f, bZ = 0.f, bN = 0.f;
        for (int k4 = 0; k4 < 64; k4 += 4) {
            floatx4 wr4 = *(const floatx4*)(wi + (u) * 64 + k4);
            floatx4 wz4 = *(const floatx4*)(wi + (64 + u) * 64 + k4);
            floatx4 wn4 = *(const floatx4*)(wi + (128 + u) * 64 + k4);
            floatx4 be4 = *(const floatx4*)(emb_b + k4);
            #pragma unroll
            for (int kk = 0; kk < 4; ++kk) {
                const float* er = emb_w + (k4 + kk) * 64;
                floatx4 e0 = *(const floatx4*)(er + q * 8);
                floatx4 e1 = *(const floatx4*)(er + q * 8 + 4);
                floatx4 e2 = *(const floatx4*)(er + 32 + q * 8);
                floatx4 e3 = *(const floatx4*)(er + 32 + q * 8 + 4);
                const float wr = wr4[kk], wz = wz4[kk], wn = wn4[kk];
                aR[0] += wr * e0; aR[1] += wr * e1; aR[2] += wr * e2; aR[3] += wr * e3;
                aZ[0] += wz * e0; aZ[1] += wz * e1; aZ[2] += wz * e2; aZ[3] += wz * e3;
                aN[0] += wn * e0; aN[1] += wn * e1; aN[2] += wn * e2; aN[3] += wn * e3;
                bR += wr * be4[kk]; bZ += wz * be4[kk]; bN += wn * be4[kk];
            }
        }
        #pragma unroll
        for (int x = 0; x < 4; ++x) {
            fR[0][x] = (_Float16)(-L2E * aR[0][x]);   fR[0][4 + x] = (_Float16)(-L2E * aR[1][x]);
            fR[1][x] = (_Float16)(-L2E * aR[2][x]);   fR[1][4 + x] = (_Float16)(-L2E * aR[3][x]);
            fZ[0][x] = (_Float16)(-L2E * aZ[0][x]);   fZ[0][4 + x] = (_Float16)(-L2E * aZ[1][x]);
            fZ[1][x] = (_Float16)(-L2E * aZ[2][x]);   fZ[1][4 + x] = (_Float16)(-L2E * aZ[3][x]);
            fNi[0][x] = (_Float16)(2*L2E * aN[0][x]); fNi[0][4 + x] = (_Float16)(2*L2E * aN[1][x]);
            fNi[1][x] = (_Float16)(2*L2E * aN[2][x]); fNi[1][4 + x] = (_Float16)(2*L2E * aN[3][x]);
        }
        fR[2]  = ldw8s(wh + (u) * 64 + q * 8, -L2E);        fR[3]  = ldw8s(wh + (u) * 64 + 32 + q * 8, -L2E);
        fZ[2]  = ldw8s(wh + (64 + u) * 64 + q * 8, -L2E);   fZ[3]  = ldw8s(wh + (64 + u) * 64 + 32 + q * 8, -L2E);
        fNh[0] = ldw8s(wh + (128 + u) * 64 + q * 8, 2*L2E); fNh[1] = ldw8s(wh + (128 + u) * 64 + 32 + q * 8, 2*L2E);
        if (q == 0) {                                // fold-bias per hidden unit u (q-invariant)
            s_btmp[u] = bR; s_btmp[64 + u] = bZ; s_btmp[128 + u] = bN;
        }
        const int oc = (c < NOUTC) ? c : 0;
        fO[0] = ldw8s(out_w + oc * 64 + q * 8, 1.f);
        fO[1] = ldw8s(out_w + oc * 64 + 32 + q * 8, 1.f);
    } else {
        const float* wi = w_ih + l * 3 * HSZ * ESZ;
        const float* wh = w_hh + l * 3 * HSZ * ESZ;
        fR[0]  = ldw8s(wi + (u) * 64 + q * 8, -L2E);        fR[1]  = ldw8s(wi + (u) * 64 + 32 + q * 8, -L2E);
        fR[2]  = ldw8s(wh + (u) * 64 + q * 8, -L2E);        fR[3]  = ldw8s(wh + (u) * 64 + 32 + q * 8, -L2E);
        fZ[0]  = ldw8s(wi + (64 + u) * 64 + q * 8, -L2E);   fZ[1]  = ldw8s(wi + (64 + u) * 64 + 32 + q * 8, -L2E);
        fZ[2]  = ldw8s(wh + (64 + u) * 64 + q * 8, -L2E);   fZ[3]  = ldw8s(wh + (64 + u) * 64 + 32 + q * 8, -L2E);
        fNi[0] = ldw8s(wi + (128 + u) * 64 + q * 8, 2*L2E); fNi[1] = ldw8s(wi + (128 + u) * 64 + 32 + q * 8, 2*L2E);
        fNh[0] = ldw8s(wh + (128 + u) * 64 + q * 8, 2*L2E); fNh[1] = ldw8s(wh + (128 + u) * 64 + 32 + q * 8, 2*L2E);
    }
    __syncthreads();                                 // staging + s_btmp visible

    // ---- per-lane bias vectors (C-init), hidden units u4..u4+3 ----
    floatx4 bR4, bZ4, bNi4, bNh4;
    if (l == 0) {
        #pragma unroll
        for (int i = 0; i < 4; ++i) {
            bR4[i]  = -L2E * (s_btmp[u4 + i] + b_ih[u4 + i] + b_hh[u4 + i]);
            bZ4[i]  = -L2E * (s_btmp[64 + u4 + i] + b_ih[64 + u4 + i] + b_hh[64 + u4 + i]);
            bNi4[i] = 2.f * L2E * (s_btmp[128 + u4 + i] + b_ih[128 + u4 + i]);
            bNh4[i] = 2.f * L2E * b_hh[128 + u4 + i];
        }
    } else {
        const int b0 = l * 192;
        floatx4 bi0 = *(const floatx4*)(b_ih + b0 + u4),       bh0 = *(const floatx4*)(b_hh + b0 + u4);
        floatx4 bi1 = *(const floatx4*)(b_ih + b0 + 64 + u4),  bh1 = *(const floatx4*)(b_hh + b0 + 64 + u4);
        floatx4 bi2 = *(const floatx4*)(b_ih + b0 + 128 + u4), bh2 = *(const floatx4*)(b_hh + b0 + 128 + u4);
        #pragma unroll
        for (int i = 0; i < 4; ++i) {
            bR4[i]  = -L2E * (bi0[i] + bh0[i]);
            bZ4[i]  = -L2E * (bi1[i] + bh1[i]);
            bNi4[i] = 2.f * L2E * bi2[i];
            bNh4[i] = 2.f * L2E * bh2[i];
        }
    }
    const float ob0 = out_b[0], ob1 = out_b[1];

    // ---- fp32 h-carry in VGPRs: ca{j}[i] = h[u4+i][batch row j*16+c] ----
    floatx4 ca0 = *(const floatx4*)(enc + (wgbase +  0 + c) * 64 + u4);
    floatx4 ca1 = *(const floatx4*)(enc + (wgbase + 16 + c) * 64 + u4);

    const int ar = c * LDW + (q << 3);               // act B-frag offset

    // one 16-row GRU cell visit: layer ll, tile j, timestep t, parity parw
    // (literal at every call site so LDS bases fold into offset immediates).
    auto visit = [&](const int ll, const int j, floatx4& cs, const int t,
                     const int parw) {
        const _Float16* hb = s_hl + ((ll * 2 + j) * 2 + (parw ^ 1)) * TB16;
        const _Float16* xb = (ll == 0) ? s_hl + ((4 + j) * 2 + (parw ^ 1)) * TB16
                                       : s_hl + (((ll - 1) * 2 + j) * 2 + parw) * TB16;
        half8 ah0 = *(const half8*)(hb + ar);
        half8 ah1 = *(const half8*)(hb + ar + 32);
        half8 bx0 = *(const half8*)(xb + ar);
        half8 bx1 = *(const half8*)(xb + ar + 32);
        floatx4 accr = bR4, accz = bZ4, accnh = bNh4;
        accr  = MFMA(fR[2], ah0, accr);   accr  = MFMA(fR[3], ah1, accr);
        accz  = MFMA(fZ[2], ah0, accz);   accz  = MFMA(fZ[3], ah1, accz);
        accnh = MFMA(fNh[0], ah0, accnh); accnh = MFMA(fNh[1], ah1, accnh);
        accr = MFMA(fR[0], bx0, accr); accr = MFMA(fR[1], bx1, accr);
        accz = MFMA(fZ[0], bx0, accz); accz = MFMA(fZ[1], bx1, accz);
        floatx4 accni = bNi4;
        accni = MFMA(fNi[0], bx0, accni); accni = MFMA(fNi[1], bx1, accni);
        _Float16* hw = s_hl + ((ll * 2 + j) * 2 + parw) * TB16 + c * LDW + u4;
        half4 hv4; floatx4 hnew;
        #pragma unroll
        for (int i = 0; i < 4; ++i) {
            const float er = __builtin_amdgcn_exp2f(accr[i]);
            const float ez = __builtin_amdgcn_exp2f(accz[i]);
            const float pr = 1.f + er, pz = 1.f + ez;
            const float qq = __builtin_amdgcn_rcpf(pr * pz);  // shared rcp
            const float rr = qq * pz;                          // = 1/(1+er)
            const float zz = qq * pr;                          // = 1/(1+ez)
            const float a  = accni[i] + rr * accnh[i];
            const float n  = 1.f - 2.f * __builtin_amdgcn_rcpf(1.f + __builtin_amdgcn_exp2f(a));
            const float hv = n + zz * (cs[i] - n);
            hnew[i] = hv; hv4[i] = (_Float16)hv;
        }
        *(half4*)hw = hv4;
        cs = hnew;
    };

    // out(t) = h2(t) @ out_w.T + out_b; L0 wave g (g<2) serves tile g.
    auto visO = [&](const int j, const int t, const int par) {
        const _Float16* xb = s_hl + ((4 + j) * 2 + par) * TB16;
        half8 b0 = *(const half8*)(xb + ar);
        half8 b1 = *(const half8*)(xb + ar + 32);
        floatx4 oa = {ob0, ob1, 0.f, 0.f};
        oa = MFMA(fO[0], b0, oa);
        oa = MFMA(fO[1], b1, oa);
        if (q == 0) {
            const long row = wgbase + j * 16 + c;
            *(floatx2*)(out + (row * TLEN + t) * NOUTC) = floatx2{oa[0], oa[1]};
        }
    };

    // ---- systolic loop: 3 slots/t, x2 unrolled so parities are literals ----
    for (int t = 0; t < TLEN; t += 2) {
        const bool vv = (t != 0);
        // ==== even t (parw 0); lagging t-1 (parw 1) ====
        if (l == 0)      visit(0, 0, ca0, t, 0);
        else if (l == 2) { if (vv) visit(2, 1, ca1, t - 1, 1); }
        SBAR();
        if (l == 0)      visit(0, 1, ca1, t, 0);
        else if (l == 1) visit(1, 0, ca0, t, 0);
        SBAR();
        if (l == 0)      { if (vv && g < 2) visO(g, t - 1, 1); }
        else if (l == 1) visit(1, 1, ca1, t, 0);
        else             visit(2, 0, ca0, t, 0);
        SBAR();
        // ==== odd t+1 (parw 1); lagging t (parw 0) ====
        if (l == 0)      visit(0, 0, ca0, t + 1, 1);
        else if (l == 2) visit(2, 1, ca1, t, 0);
        SBAR();
        if (l == 0)      visit(0, 1, ca1, t + 1, 1);
        else if (l == 1) visit(1, 0, ca0, t + 1, 1);
        SBAR();
        if (l == 0)      { if (g < 2) visO(g, t, 0); }
        else if (l == 1) visit(1, 1, ca1, t + 1, 1);
        else             visit(2, 0, ca0, t + 1, 1);
        SBAR();
    }

    // ---- epilogue: finish t = 127 (parity 1) ----
    if (l == 2)           visit(2, 1, ca1, TLEN - 1, 1);
    else if (l == 0 && g == 0) visO(0, TLEN - 1, 1);
    SBAR();
    if (l == 0 && g == 1) visO(1, TLEN - 1, 1);
}

extern "C" void kernel_launch(void* const* d_in, const int* in_sizes, int n_in,
                              void* d_out, int out_size, void* d_ws, size_t ws_size,
                              hipStream_t stream) {
    (void)in_sizes; (void)n_in; (void)d_ws; (void)ws_size; (void)out_size;
    const int grid = 16384 / 32;   // 512 workgroups, 2 per CU
    gru_pipe<<<grid, 768, 0, stream>>>(
        (const float*)d_in[0],  // agentFutureTrajEnc
        (const float*)d_in[1],  // emb_w
        (const float*)d_in[2],  // emb_b
        (const float*)d_in[3],  // w_ih
        (const float*)d_in[4],  // w_hh
        (const float*)d_in[5],  // b_ih
        (const float*)d_in[6],  // b_hh
        (const float*)d_in[7],  // out_w
        (const float*)d_in[8],  // out_b
        (float*)d_out);
}

// Round 5
// 460.700 us; speedup vs baseline: 2.2548x; 1.1880x over previous
//
#include <hip/hip_runtime.h>

// FutureTrajDecoder: 3-layer GRU rollout, B=16384, ES=HS=64, T=128, NOUT=2.
// R18: 3 barrier-slots per timestep (was 4), 4 tiles with phases (0,1,2,0).
// Evidence: R13=R14=R15=450us across 3 sync schemes; R17's accidental
// serialization measured stage wall = fixed tail (~600 cyc dep latency +
// issue) PER SLOT, and TLP is hard-capped at 3 waves/SIMD (2 WGs/CU never
// co-schedule for 768-thr barrier WGs; >12 waves in-WG spills VGPR file).
// So: keep 12 waves, same math, FEWER slots. The chain L0->L1->L2->L0(t+1)
// needs >=3 slots/t; R15 used 4. With tile phases p_j=(0,1,2,0) a legal
// 3-slot schedule exists; one layer per phase runs a FUSED double visit
// (tiles {0,3}) so every phase has exactly 4 visits (balanced), and the
// two fused chains interleave (2x ILP) without adding a slot.
// Schedule frame t, phase p (cells MFMA'd+gated+written in that slot):
//   p0: L0:(t,0)+(t,3) [fused]; L1:(t-1,2); L2:(t-1,1); out(t-1,0|3) on L0 g0|g3
//   p1: L0:(t,1); L1:(t,0)+(t,3); L2:(t-1,2);           out(t-1,1) on L0 g1
//   p2: L0:(t,2); L1:(t,1); L2:(t,0)+(t,3);             out(t-1,2) on L0 g2
// Deps all 1-barrier-separated (checked incl. wraparound h2(t-1,j)->L0(t,j):
// p_j+2 (write) < p_j+3 (read), h-side lag 3 slots, WAR gap >=3 slots).
// Epilogue: 3 slots finish (127)'s L1(2), L2(1), L2(2), out(127,*).
// Kept: SBAR = s_waitcnt lgkmcnt(0)+s_barrier (no vmcnt drain); rcp-merge
// gates (5 trans/elem, absmax-verified); emb folded into L0; gate scales
// folded into weights; biases in MFMA C-init; weights = A operand; fp32
// carry in VGPRs; MFMA 16x16x32 f16 fp32-accum; x-MFMAs chained.

#define ESZ   64
#define HSZ   64
#define TLEN  128
#define NOUTC 2
#define LDW   72              // fp16 row stride (144 B)
#define TB16  (16*LDW)        // one 16-row activation tile buffer
#define L2E   1.44269504f

typedef _Float16 half8 __attribute__((ext_vector_type(8)));
typedef _Float16 half4 __attribute__((ext_vector_type(4)));
typedef float    floatx4 __attribute__((ext_vector_type(4)));
typedef float    floatx2 __attribute__((ext_vector_type(2)));

#define MFMA(a, b, c) __builtin_amdgcn_mfma_f32_16x16x32_f16((a), (b), (c), 0, 0, 0)

// LDS-ordering barrier WITHOUT vmcnt drain (global stores stay in flight).
#define SBAR() asm volatile("s_waitcnt lgkmcnt(0)\n\ts_barrier" ::: "memory")

__global__ __launch_bounds__(768, 3) void gru_pipe(
    const float* __restrict__ enc,     // (B, 64)
    const float* __restrict__ emb_w,   // (64, 64)
    const float* __restrict__ emb_b,   // (64,)
    const float* __restrict__ w_ih,    // (3, 192, 64)
    const float* __restrict__ w_hh,    // (3, 192, 64)
    const float* __restrict__ b_ih,    // (3, 192)
    const float* __restrict__ b_hh,    // (3, 192)
    const float* __restrict__ out_w,   // (2, 64)
    const float* __restrict__ out_b,   // (2,)
    float* __restrict__ out)           // (B, 128, 2)
{
    __shared__ _Float16 s_hl[3 * 4 * 2 * TB16]; // h_l fp16 [layer][tile][parity]
    __shared__ float    s_btmp[3 * 64];          // folded emb bias (fp32)

    const int tid  = threadIdx.x;
    const int wave = tid >> 6, lane = tid & 63;
    const int l = wave >> 2, g = wave & 3;      // layer-stage 0..2, colgroup 0..3
    const int q = lane >> 4, c = lane & 15;
    const int u  = (g << 4) | c;                // weight row this lane loads
    const int u4 = (g << 4) | (q << 2);         // first hidden unit this lane OWNS
    const long wgbase = (long)blockIdx.x * 64;

    // ---- stage enc (= x(0) = h(-1)) into all layer buffers, parity 1 ----
    if (tid < 512) {
        const int row = tid >> 3, k0 = (tid & 7) << 3;   // 8 floats per thread
        const int j = row >> 4, rr = row & 15;
        const float* p = enc + (wgbase + row) * ESZ + k0;
        floatx4 s0 = *(const floatx4*)p;
        floatx4 s1 = *(const floatx4*)(p + 4);
        half8 v;
        #pragma unroll
        for (int x = 0; x < 4; ++x) { v[x] = (_Float16)s0[x]; v[4 + x] = (_Float16)s1[x]; }
        #pragma unroll
        for (int ly = 0; ly < 3; ++ly)
            *(half8*)&s_hl[((ly * 4 + j) * 2 + 1) * TB16 + rr * LDW + k0] = v;
    }

    // ---- weight fragments (A-operand) ----
    auto ldw8s = [&](const float* p, float sc) {
        floatx4 a = *(const floatx4*)p, b = *(const floatx4*)(p + 4);
        half8 v;
        #pragma unroll
        for (int x = 0; x < 4; ++x) { v[x] = (_Float16)(a[x] * sc); v[4 + x] = (_Float16)(b[x] * sc); }
        return v;
    };
    half8 fR[4], fZ[4], fNi[2], fNh[2], fO[2];
    fO[0] = fO[1] = half8{};
    if (l == 0) {
        // ---- fold W' = W_ih0 @ W_e (fp32), b' = W_ih0 @ b_e ----
        const float* wi = w_ih;
        const float* wh = w_hh;
        floatx4 aR[4], aZ[4], aN[4];
        #pragma unroll
        for (int x = 0; x < 4; ++x) { aR[x] = {0,0,0,0}; aZ[x] = {0,0,0,0}; aN[x] = {0,0,0,0}; }
        float bR = 0.f, bZ = 0.f, bN = 0.f;
        for (int k4 = 0; k4 < 64; k4 += 4) {
            floatx4 wr4 = *(const floatx4*)(wi + (u) * 64 + k4);
            floatx4 wz4 = *(const floatx4*)(wi + (64 + u) * 64 + k4);
            floatx4 wn4 = *(const floatx4*)(wi + (128 + u) * 64 + k4);
            floatx4 be4 = *(const floatx4*)(emb_b + k4);
            #pragma unroll
            for (int kk = 0; kk < 4; ++kk) {
                const float* er = emb_w + (k4 + kk) * 64;
                floatx4 e0 = *(const floatx4*)(er + q * 8);
                floatx4 e1 = *(const floatx4*)(er + q * 8 + 4);
                floatx4 e2 = *(const floatx4*)(er + 32 + q * 8);
                floatx4 e3 = *(const floatx4*)(er + 32 + q * 8 + 4);
                const float wr = wr4[kk], wz = wz4[kk], wn = wn4[kk];
                aR[0] += wr * e0; aR[1] += wr * e1; aR[2] += wr * e2; aR[3] += wr * e3;
                aZ[0] += wz * e0; aZ[1] += wz * e1; aZ[2] += wz * e2; aZ[3] += wz * e3;
                aN[0] += wn * e0; aN[1] += wn * e1; aN[2] += wn * e2; aN[3] += wn * e3;
                bR += wr * be4[kk]; bZ += wz * be4[kk]; bN += wn * be4[kk];
            }
        }
        #pragma unroll
        for (int x = 0; x < 4; ++x) {
            fR[0][x] = (_Float16)(-L2E * aR[0][x]);   fR[0][4 + x] = (_Float16)(-L2E * aR[1][x]);
            fR[1][x] = (_Float16)(-L2E * aR[2][x]);   fR[1][4 + x] = (_Float16)(-L2E * aR[3][x]);
            fZ[0][x] = (_Float16)(-L2E * aZ[0][x]);   fZ[0][4 + x] = (_Float16)(-L2E * aZ[1][x]);
            fZ[1][x] = (_Float16)(-L2E * aZ[2][x]);   fZ[1][4 + x] = (_Float16)(-L2E * aZ[3][x]);
            fNi[0][x] = (_Float16)(2*L2E * aN[0][x]); fNi[0][4 + x] = (_Float16)(2*L2E * aN[1][x]);
            fNi[1][x] = (_Float16)(2*L2E * aN[2][x]); fNi[1][4 + x] = (_Float16)(2*L2E * aN[3][x]);
        }
        fR[2]  = ldw8s(wh + (u) * 64 + q * 8, -L2E);        fR[3]  = ldw8s(wh + (u) * 64 + 32 + q * 8, -L2E);
        fZ[2]  = ldw8s(wh + (64 + u) * 64 + q * 8, -L2E);   fZ[3]  = ldw8s(wh + (64 + u) * 64 + 32 + q * 8, -L2E);
        fNh[0] = ldw8s(wh + (128 + u) * 64 + q * 8, 2*L2E); fNh[1] = ldw8s(wh + (128 + u) * 64 + 32 + q * 8, 2*L2E);
        if (q == 0) {                                // fold-bias per hidden unit u (q-invariant)
            s_btmp[u] = bR; s_btmp[64 + u] = bZ; s_btmp[128 + u] = bN;
        }
        const int oc = (c < NOUTC) ? c : 0;
        fO[0] = ldw8s(out_w + oc * 64 + q * 8, 1.f);
        fO[1] = ldw8s(out_w + oc * 64 + 32 + q * 8, 1.f);
    } else {
        const float* wi = w_ih + l * 3 * HSZ * ESZ;
        const float* wh = w_hh + l * 3 * HSZ * ESZ;
        fR[0]  = ldw8s(wi + (u) * 64 + q * 8, -L2E);        fR[1]  = ldw8s(wi + (u) * 64 + 32 + q * 8, -L2E);
        fR[2]  = ldw8s(wh + (u) * 64 + q * 8, -L2E);        fR[3]  = ldw8s(wh + (u) * 64 + 32 + q * 8, -L2E);
        fZ[0]  = ldw8s(wi + (64 + u) * 64 + q * 8, -L2E);   fZ[1]  = ldw8s(wi + (64 + u) * 64 + 32 + q * 8, -L2E);
        fZ[2]  = ldw8s(wh + (64 + u) * 64 + q * 8, -L2E);   fZ[3]  = ldw8s(wh + (64 + u) * 64 + 32 + q * 8, -L2E);
        fNi[0] = ldw8s(wi + (128 + u) * 64 + q * 8, 2*L2E); fNi[1] = ldw8s(wi + (128 + u) * 64 + 32 + q * 8, 2*L2E);
        fNh[0] = ldw8s(wh + (128 + u) * 64 + q * 8, 2*L2E); fNh[1] = ldw8s(wh + (128 + u) * 64 + 32 + q * 8, 2*L2E);
    }
    __syncthreads();                                 // staging + s_btmp visible

    // ---- per-lane bias vectors (C-init), hidden units u4..u4+3 ----
    floatx4 bR4, bZ4, bNi4, bNh4;
    if (l == 0) {
        #pragma unroll
        for (int i = 0; i < 4; ++i) {
            bR4[i]  = -L2E * (s_btmp[u4 + i] + b_ih[u4 + i] + b_hh[u4 + i]);
            bZ4[i]  = -L2E * (s_btmp[64 + u4 + i] + b_ih[64 + u4 + i] + b_hh[64 + u4 + i]);
            bNi4[i] = 2.f * L2E * (s_btmp[128 + u4 + i] + b_ih[128 + u4 + i]);
            bNh4[i] = 2.f * L2E * b_hh[128 + u4 + i];
        }
    } else {
        const int b0 = l * 192;
        floatx4 bi0 = *(const floatx4*)(b_ih + b0 + u4),       bh0 = *(const floatx4*)(b_hh + b0 + u4);
        floatx4 bi1 = *(const floatx4*)(b_ih + b0 + 64 + u4),  bh1 = *(const floatx4*)(b_hh + b0 + 64 + u4);
        floatx4 bi2 = *(const floatx4*)(b_ih + b0 + 128 + u4), bh2 = *(const floatx4*)(b_hh + b0 + 128 + u4);
        #pragma unroll
        for (int i = 0; i < 4; ++i) {
            bR4[i]  = -L2E * (bi0[i] + bh0[i]);
            bZ4[i]  = -L2E * (bi1[i] + bh1[i]);
            bNi4[i] = 2.f * L2E * bi2[i];
            bNh4[i] = 2.f * L2E * bh2[i];
        }
    }
    const float ob0 = out_b[0], ob1 = out_b[1];

    // ---- fp32 h-carry in VGPRs: ca{j}[i] = h[u4+i][batch row j*16+c] ----
    floatx4 ca0 = *(const floatx4*)(enc + (wgbase +  0 + c) * 64 + u4);
    floatx4 ca1 = *(const floatx4*)(enc + (wgbase + 16 + c) * 64 + u4);
    floatx4 ca2 = *(const floatx4*)(enc + (wgbase + 32 + c) * 64 + u4);
    floatx4 ca3 = *(const floatx4*)(enc + (wgbase + 48 + c) * 64 + u4);

    const int ar = c * LDW + (q << 3);               // act B-frag offset

    // gate nonlinearity (rcp-merge: 5 trans/elem), writes h to LDS + carry
    auto gates = [&](floatx4& accr, floatx4& accz, floatx4& accni, floatx4& accnh,
                     floatx4& cs, _Float16* hw) {
        half4 hv4; floatx4 hnew;
        #pragma unroll
        for (int i = 0; i < 4; ++i) {
            const float er = __builtin_amdgcn_exp2f(accr[i]);
            const float ez = __builtin_amdgcn_exp2f(accz[i]);
            const float pr = 1.f + er, pz = 1.f + ez;
            const float qq = __builtin_amdgcn_rcpf(pr * pz);  // shared rcp
            const float rr = qq * pz;                          // = 1/(1+er)
            const float zz = qq * pr;                          // = 1/(1+ez)
            const float a  = accni[i] + rr * accnh[i];
            const float n  = 1.f - 2.f * __builtin_amdgcn_rcpf(1.f + __builtin_amdgcn_exp2f(a));
            const float hv = n + zz * (cs[i] - n);
            hnew[i] = hv; hv4[i] = (_Float16)hv;
        }
        *(half4*)hw = hv4;
        cs = hnew;
    };

    // single 16-row GRU cell visit: layer ll, tile j, timestep t, parity parw
    auto visit = [&](const int ll, const int j, floatx4& cs, const int t,
                     const int parw) {
        const _Float16* hb = s_hl + ((ll * 4 + j) * 2 + (parw ^ 1)) * TB16;
        const _Float16* xb = (ll == 0) ? s_hl + ((8 + j) * 2 + (parw ^ 1)) * TB16
                                       : s_hl + (((ll - 1) * 4 + j) * 2 + parw) * TB16;
        half8 ah0 = *(const half8*)(hb + ar);
        half8 ah1 = *(const half8*)(hb + ar + 32);
        half8 bx0 = *(const half8*)(xb + ar);
        half8 bx1 = *(const half8*)(xb + ar + 32);
        floatx4 accr = bR4, accz = bZ4, accnh = bNh4;
        accr  = MFMA(fR[2], ah0, accr);   accr  = MFMA(fR[3], ah1, accr);
        accz  = MFMA(fZ[2], ah0, accz);   accz  = MFMA(fZ[3], ah1, accz);
        accnh = MFMA(fNh[0], ah0, accnh); accnh = MFMA(fNh[1], ah1, accnh);
        accr = MFMA(fR[0], bx0, accr); accr = MFMA(fR[1], bx1, accr);
        accz = MFMA(fZ[0], bx0, accz); accz = MFMA(fZ[1], bx1, accz);
        floatx4 accni = bNi4;
        accni = MFMA(fNi[0], bx0, accni); accni = MFMA(fNi[1], bx1, accni);
        _Float16* hw = s_hl + ((ll * 4 + j) * 2 + parw) * TB16 + c * LDW + u4;
        gates(accr, accz, accni, accnh, cs, hw);
    };

    // fused double visit (tiles ja, jb): 8 ds_reads -> 24 MFMAs -> 2 gate
    // blocks; the two independent chains interleave for 2x ILP in-slot.
    auto visit2 = [&](const int ll, const int ja, floatx4& csa,
                      const int jb, floatx4& csb, const int t, const int parw) {
        const _Float16* hbA = s_hl + ((ll * 4 + ja) * 2 + (parw ^ 1)) * TB16;
        const _Float16* hbB = s_hl + ((ll * 4 + jb) * 2 + (parw ^ 1)) * TB16;
        const _Float16* xbA = (ll == 0) ? s_hl + ((8 + ja) * 2 + (parw ^ 1)) * TB16
                                        : s_hl + (((ll - 1) * 4 + ja) * 2 + parw) * TB16;
        const _Float16* xbB = (ll == 0) ? s_hl + ((8 + jb) * 2 + (parw ^ 1)) * TB16
                                        : s_hl + (((ll - 1) * 4 + jb) * 2 + parw) * TB16;
        half8 ahA0 = *(const half8*)(hbA + ar), ahA1 = *(const half8*)(hbA + ar + 32);
        half8 bxA0 = *(const half8*)(xbA + ar), bxA1 = *(const half8*)(xbA + ar + 32);
        half8 ahB0 = *(const half8*)(hbB + ar), ahB1 = *(const half8*)(hbB + ar + 32);
        half8 bxB0 = *(const half8*)(xbB + ar), bxB1 = *(const half8*)(xbB + ar + 32);
        floatx4 accrA = bR4, acczA = bZ4, accnhA = bNh4;
        floatx4 accrB = bR4, acczB = bZ4, accnhB = bNh4;
        accrA  = MFMA(fR[2], ahA0, accrA);   accrA  = MFMA(fR[3], ahA1, accrA);
        accrB  = MFMA(fR[2], ahB0, accrB);   accrB  = MFMA(fR[3], ahB1, accrB);
        acczA  = MFMA(fZ[2], ahA0, acczA);   acczA  = MFMA(fZ[3], ahA1, acczA);
        acczB  = MFMA(fZ[2], ahB0, acczB);   acczB  = MFMA(fZ[3], ahB1, acczB);
        accnhA = MFMA(fNh[0], ahA0, accnhA); accnhA = MFMA(fNh[1], ahA1, accnhA);
        accnhB = MFMA(fNh[0], ahB0, accnhB); accnhB = MFMA(fNh[1], ahB1, accnhB);
        accrA = MFMA(fR[0], bxA0, accrA); accrA = MFMA(fR[1], bxA1, accrA);
        accrB = MFMA(fR[0], bxB0, accrB); accrB = MFMA(fR[1], bxB1, accrB);
        acczA = MFMA(fZ[0], bxA0, acczA); acczA = MFMA(fZ[1], bxA1, acczA);
        acczB = MFMA(fZ[0], bxB0, acczB); acczB = MFMA(fZ[1], bxB1, acczB);
        floatx4 accniA = bNi4, accniB = bNi4;
        accniA = MFMA(fNi[0], bxA0, accniA); accniA = MFMA(fNi[1], bxA1, accniA);
        accniB = MFMA(fNi[0], bxB0, accniB); accniB = MFMA(fNi[1], bxB1, accniB);
        _Float16* hwA = s_hl + ((ll * 4 + ja) * 2 + parw) * TB16 + c * LDW + u4;
        _Float16* hwB = s_hl + ((ll * 4 + jb) * 2 + parw) * TB16 + c * LDW + u4;
        gates(accrA, acczA, accniA, accnhA, csa, hwA);
        gates(accrB, acczB, accniB, accnhB, csb, hwB);
    };

    // out(t) = h2(t) @ out_w.T + out_b; called on L0 wave g==j.
    auto visO = [&](const int j, const int t, const int par) {
        const _Float16* xb = s_hl + ((8 + j) * 2 + par) * TB16;
        half8 b0 = *(const half8*)(xb + ar);
        half8 b1 = *(const half8*)(xb + ar + 32);
        floatx4 oa = {ob0, ob1, 0.f, 0.f};
        oa = MFMA(fO[0], b0, oa);
        oa = MFMA(fO[1], b1, oa);
        if (q == 0) {
            const long row = wgbase + j * 16 + c;
            *(floatx2*)(out + (row * TLEN + t) * NOUTC) = floatx2{oa[0], oa[1]};
        }
    };

    // ---- 3-slot systolic loop, x2 unrolled so parities are literals ----
    for (int t = 0; t < TLEN; t += 2) {
        const bool vv = (t != 0);
        // ==== frame t (parw 0), lagging frame t-1 (parw 1) ====
        // phase 0
        if (l == 0) {
            visit2(0, 0, ca0, 3, ca3, t, 0);
            if (vv && g == 0) visO(0, t - 1, 1);
            else if (vv && g == 3) visO(3, t - 1, 1);
        } else if (l == 1) { if (vv) visit(1, 2, ca2, t - 1, 1); }
        else               { if (vv) visit(2, 1, ca1, t - 1, 1); }
        SBAR();
        // phase 1
        if (l == 0) {
            visit(0, 1, ca1, t, 0);
            if (vv && g == 1) visO(1, t - 1, 1);
        } else if (l == 1) visit2(1, 0, ca0, 3, ca3, t, 0);
        else               { if (vv) visit(2, 2, ca2, t - 1, 1); }
        SBAR();
        // phase 2
        if (l == 0) {
            visit(0, 2, ca2, t, 0);
            if (vv && g == 2) visO(2, t - 1, 1);
        } else if (l == 1) visit(1, 1, ca1, t, 0);
        else               visit2(2, 0, ca0, 3, ca3, t, 0);
        SBAR();
        // ==== frame t+1 (parw 1), lagging frame t (parw 0) ====
        // phase 0
        if (l == 0) {
            visit2(0, 0, ca0, 3, ca3, t + 1, 1);
            if (g == 0) visO(0, t, 0);
            else if (g == 3) visO(3, t, 0);
        } else if (l == 1) visit(1, 2, ca2, t, 0);
        else               visit(2, 1, ca1, t, 0);
        SBAR();
        // phase 1
        if (l == 0) {
            visit(0, 1, ca1, t + 1, 1);
            if (g == 1) visO(1, t, 0);
        } else if (l == 1) visit2(1, 0, ca0, 3, ca3, t + 1, 1);
        else               visit(2, 2, ca2, t, 0);
        SBAR();
        // phase 2
        if (l == 0) {
            visit(0, 2, ca2, t + 1, 1);
            if (g == 2) visO(2, t, 0);
        } else if (l == 1) visit(1, 1, ca1, t + 1, 1);
        else               visit2(2, 0, ca0, 3, ca3, t + 1, 1);
        SBAR();
    }

    // ---- epilogue: finish frame-128 leftovers for t = 127 (parity 1) ----
    if (l == 1)                visit(1, 2, ca2, TLEN - 1, 1);
    else if (l == 2)           visit(2, 1, ca1, TLEN - 1, 1);
    else if (l == 0 && g == 0) visO(0, TLEN - 1, 1);
    else if (l == 0 && g == 3) visO(3, TLEN - 1, 1);
    SBAR();
    if (l == 2)                visit(2, 2, ca2, TLEN - 1, 1);
    else if (l == 0 && g == 1) visO(1, TLEN - 1, 1);
    SBAR();
    if (l == 0 && g == 2)      visO(2, TLEN - 1, 1);
}

extern "C" void kernel_launch(void* const* d_in, const int* in_sizes, int n_in,
                              void* d_out, int out_size, void* d_ws, size_t ws_size,
                              hipStream_t stream) {
    (void)in_sizes; (void)n_in; (void)d_ws; (void)ws_size; (void)out_size;
    const int grid = 16384 / 64;   // 256 workgroups, 1 per CU
    gru_pipe<<<grid, 768, 0, stream>>>(
        (const float*)d_in[0],  // agentFutureTrajEnc
        (const float*)d_in[1],  // emb_w
        (const float*)d_in[2],  // emb_b
        (const float*)d_in[3],  // w_ih
        (const float*)d_in[4],  // w_hh
        (const float*)d_in[5],  // b_ih
        (const float*)d_in[6],  // b_hh
        (const float*)d_in[7],  // out_w
        (const float*)d_in[8],  // out_b
        (float*)d_out);
}